// Round 3
// baseline (111.805 us; speedup 1.0000x reference)
//
#include <hip/hip_runtime.h>

// TopNGating: B=2, N=4096, DIM=2048, 8 experts, top-2, cap=640
// Outputs (concat): dispatch[2,4096,8,640], combine[2,4096,8,640], balance_loss, router_z_loss

#define DIMX 2048
#define NG   8
#define NB   2
#define NSEQ 4096
#define NTOK (NB*NSEQ)
#define CAPE 640
#define ROW  (NG*CAPE)                 // 5120 floats per token per tensor
#define DCNT ((size_t)NTOK*ROW)        // 41943040 floats per dense output

struct Ws {
  int   pk[NTOK];                 // e0 | e1<<4 | routed1<<8
  float g0[NTOK];                 // renormalized top-1 gate
  float g1[NTOK];                 // renormalized top-2 gate
  float z2[NTOK];                 // lse^2 per token
  float raws[(size_t)NTOK*NG];    // raw softmax gates
  float proxy[16];                // per (b,e) sum of raw gates over n
  int   cnt0[16];                 // per (b,e) capacity-clipped top-1 count
};

// ---------------- fused: gate logits+softmax+top2+routing  AND  zero-fill of outputs ----------------
// 1024 blocks x 512 threads. Each block: stages W (64KB LDS, 2 blocks/CU), gates 8 tokens
// (one wave per token), and zero-fills a grid-stride slice of the 335.5MB output.
// Even/odd blocks swap the order so HBM reads and writes overlap.
__global__ __launch_bounds__(512) void kmain(const float* __restrict__ x,
                                             const float* __restrict__ W,
                                             const float* __restrict__ probs,
                                             Ws* __restrict__ ws,
                                             float4* __restrict__ out4) {
  __shared__ float4 Wl[NG * 512];
  int tid = threadIdx.x;
  for (int i = tid; i < NG * 512; i += 512) Wl[i] = ((const float4*)W)[i];
  __syncthreads();

  int wave = tid >> 6, lane = tid & 63;
  int token = blockIdx.x * 8 + wave;            // grid = NTOK/8 = 1024 blocks

  const long n4 = (long)(2 * DCNT) / 4;         // 20971520 float4s
  const long zbase = (long)blockIdx.x * 512 + tid;
  const long zstr  = 512L * (NTOK / 8);
  const float4 zv = make_float4(0.f, 0.f, 0.f, 0.f);

  if (blockIdx.x & 1) {                         // odd blocks: zero first
    for (long i = zbase; i < n4; i += zstr) out4[i] = zv;
  }

  { // ---- gate ----
    const float4* xp = (const float4*)(x + (size_t)token * DIMX);
    float4 xv[8];
#pragma unroll
    for (int j = 0; j < 8; ++j) xv[j] = xp[j * 64 + lane];   // coalesced 1KB/instr

    float acc[NG] = {0.f,0.f,0.f,0.f,0.f,0.f,0.f,0.f};
#pragma unroll
    for (int j = 0; j < 8; ++j) {
      float4 xj = xv[j];
#pragma unroll
      for (int e = 0; e < NG; ++e) {
        float4 w = Wl[e * 512 + j * 64 + lane];
        acc[e] = fmaf(xj.x, w.x, acc[e]);
        acc[e] = fmaf(xj.y, w.y, acc[e]);
        acc[e] = fmaf(xj.z, w.z, acc[e]);
        acc[e] = fmaf(xj.w, w.w, acc[e]);
      }
    }
#pragma unroll
    for (int e = 0; e < NG; ++e) {
#pragma unroll
      for (int off = 32; off > 0; off >>= 1) acc[e] += __shfl_xor(acc[e], off, 64);
    }

    // softmax over 8 gates (wave-uniform, redundant on all lanes)
    float m = acc[0];
#pragma unroll
    for (int e = 1; e < NG; ++e) m = fmaxf(m, acc[e]);
    float ex[NG], s = 0.f;
#pragma unroll
    for (int e = 0; e < NG; ++e) { ex[e] = expf(acc[e] - m); s += ex[e]; }
    float raw[NG];
#pragma unroll
    for (int e = 0; e < NG; ++e) raw[e] = ex[e] / s;

    // top-2, ties -> lowest index (strict >)
    int e0i = 0; float g0v = raw[0];
#pragma unroll
    for (int e = 1; e < NG; ++e) if (raw[e] > g0v) { g0v = raw[e]; e0i = e; }
    int e1i = -1; float g1v = -1.f;
#pragma unroll
    for (int e = 0; e < NG; ++e) if (e != e0i && raw[e] > g1v) { g1v = raw[e]; e1i = e; }

    float denom = g0v + g1v;
    if (denom < 1e-9f) denom = 1e-9f;
    float g0n = g0v / denom, g1n = g1v / denom;

    int b = token >> 12, n = token & (NSEQ - 1);
    float p1 = probs[NB * NSEQ + b * NSEQ + n];   // probs[1][b][n]
    int r = (p1 < (g1n / 0.2f)) ? 1 : 0;          // threshold_train = 0.2

    float lse = m + logf(s);

    if (lane < NG) ws->raws[(size_t)token * NG + lane] = raw[lane];
    if (lane == 0) {
      ws->pk[token] = e0i | (e1i << 4) | (r << 8);
      ws->g0[token] = g0n;  ws->g1[token] = g1n;
      ws->z2[token] = lse * lse;
    }
  }

  if (!(blockIdx.x & 1)) {                      // even blocks: zero after
    for (long i = zbase; i < n4; i += zstr) out4[i] = zv;
  }
}

// ---------------- per-(b,e) exclusive prefix scans + direct scatter of nonzeros ----------------
__global__ __launch_bounds__(256) void kscan(const Ws* __restrict__ wsc,
                                             Ws* __restrict__ ws,
                                             float* __restrict__ out) {
  __shared__ int   wtot[4];
  __shared__ float wsum[4];
  int be = blockIdx.x, b = be >> 3, e = be & 7;
  int t = threadIdx.x, wave = t >> 6, lane = t & 63;
  int base = b * NSEQ;

  // each thread owns 16 consecutive tokens; wave covers contiguous 4KB -> coalesced int4
  int pk[16];
  {
    const int4* pp = (const int4*)(wsc->pk + base + t * 16);
#pragma unroll
    for (int j = 0; j < 4; ++j) {
      int4 v = pp[j];
      pk[4*j] = v.x; pk[4*j+1] = v.y; pk[4*j+2] = v.z; pk[4*j+3] = v.w;
    }
  }

  // density_1_proxy partial: sum raw gates for this (b,e)
  float ps = 0.f;
#pragma unroll
  for (int i = 0; i < 16; ++i) ps += wsc->raws[(size_t)(base + t * 16 + i) * NG + e];
#pragma unroll
  for (int off = 32; off > 0; off >>= 1) ps += __shfl_xor(ps, off, 64);
  if (lane == 0) wsum[wave] = ps;

  // ---- k = 0 (always routed) ----
  int cnt = 0;
#pragma unroll
  for (int i = 0; i < 16; ++i) cnt += ((pk[i] & 15) == e);
  int incl = cnt;
#pragma unroll
  for (int off = 1; off < 64; off <<= 1) { int v = __shfl_up(incl, off, 64); if (lane >= off) incl += v; }
  if (lane == 63) wtot[wave] = incl;
  __syncthreads();
  int woff = 0, tot = 0;
#pragma unroll
  for (int w = 0; w < 4; ++w) { int v = wtot[w]; tot += v; if (w < wave) woff += v; }
  int c0 = min(tot, CAPE);
  int p = woff + incl - cnt;          // exclusive prefix for this thread's first token
#pragma unroll
  for (int i = 0; i < 16; ++i) {
    int nn = t * 16 + i;
    if ((pk[i] & 15) == e) {
      if (p < CAPE) {
        size_t o = (size_t)(base + nn) * ROW + e * CAPE + p;
        out[o]        = 1.f;                       // dispatch
        out[DCNT + o] = wsc->g0[base + nn];        // combine
      }
      ++p;
    }
  }
  __syncthreads();   // wtot reuse

  // ---- k = 1 (offset by capacity-clipped top-1 count) ----
  cnt = 0;
#pragma unroll
  for (int i = 0; i < 16; ++i) cnt += ((((pk[i] >> 4) & 15) == e) && (pk[i] & 0x100));
  incl = cnt;
#pragma unroll
  for (int off = 1; off < 64; off <<= 1) { int v = __shfl_up(incl, off, 64); if (lane >= off) incl += v; }
  if (lane == 63) wtot[wave] = incl;
  __syncthreads();
  woff = 0;
#pragma unroll
  for (int w = 0; w < 4; ++w) { int v = wtot[w]; if (w < wave) woff += v; }
  p = woff + incl - cnt;
#pragma unroll
  for (int i = 0; i < 16; ++i) {
    int nn = t * 16 + i;
    if ((((pk[i] >> 4) & 15) == e) && (pk[i] & 0x100)) {
      int q = p + c0;
      if (q < CAPE) {
        size_t o = (size_t)(base + nn) * ROW + e * CAPE + q;
        out[o]        = 1.f;                       // dispatch
        out[DCNT + o] = wsc->g1[base + nn];        // combine
      }
      ++p;
    }
  }

  if (t == 0) {
    ws->proxy[be] = wsum[0] + wsum[1] + wsum[2] + wsum[3];
    ws->cnt0[be]  = c0;
  }
}

// ---------------- losses ----------------
__global__ __launch_bounds__(256) void kloss(const Ws* __restrict__ ws, float* __restrict__ outs) {
  __shared__ float red[256];
  int t = threadIdx.x;
  float s = 0.f;
  const float4* zz = (const float4*)ws->z2;
  for (int i = t; i < NTOK / 4; i += 256) { float4 v = zz[i]; s += v.x + v.y + v.z + v.w; }
  red[t] = s; __syncthreads();
  for (int st = 128; st > 0; st >>= 1) { if (t < st) red[t] += red[t + st]; __syncthreads(); }
  if (t == 0) {
    float bal = 0.f;
    for (int i = 0; i < 16; ++i)
      bal += (ws->proxy[i] * (1.f / NSEQ)) * ((float)ws->cnt0[i] * (1.f / NSEQ));
    outs[0] = bal * (64.f / 16.f);     // mean over 16 (b,e) then * NUM_GATES^2
    outs[1] = red[0] / (float)NTOK;
  }
}

extern "C" void kernel_launch(void* const* d_in, const int* in_sizes, int n_in,
                              void* d_out, int out_size, void* d_ws, size_t ws_size,
                              hipStream_t stream) {
  const float* x     = (const float*)d_in[0];
  const float* W     = (const float*)d_in[1];
  const float* probs = (const float*)d_in[2];
  float* out = (float*)d_out;
  Ws* ws = (Ws*)d_ws;

  kmain<<<NTOK / 8, 512, 0, stream>>>(x, W, probs, ws, (float4*)out);
  kscan<<<16, 256, 0, stream>>>(ws, ws, out);
  kloss<<<1, 256, 0, stream>>>(ws, out + 2 * DCNT);
}